// Round 15
// baseline (256.355 us; speedup 1.0000x reference)
//
#include <hip/hip_runtime.h>
#include <hip/hip_bf16.h>
#include <math.h>
#include <stdint.h>

#define NB 2
#define NS 2048
#define NH 16
#define NDH 128
#define NDR 64
#define NHID 2048
#define NC 512

typedef unsigned short u16;
typedef short short8 __attribute__((ext_vector_type(8)));
typedef short short4v __attribute__((ext_vector_type(4)));
typedef float f32x4 __attribute__((ext_vector_type(4)));
typedef float f32x16 __attribute__((ext_vector_type(16)));
typedef int int2v __attribute__((ext_vector_type(2)));

#define SC2 0.10411757f   /* (1/sqrt(192)) * log2(e) */

template <int V> struct IC { static constexpr int value = V; };

__device__ __forceinline__ u16 f2bf(float f) {
  union { float f; uint32_t u; } c; c.f = f;
  uint32_t u = c.u + 0x7fffu + ((c.u >> 16) & 1u);
  return (u16)(u >> 16);
}
__device__ __forceinline__ void async16(const void* g, void* l) {
  __builtin_amdgcn_global_load_lds((const __attribute__((address_space(1))) void*)g,
                                   (__attribute__((address_space(3))) void*)l, 16, 0, 0);
}
__device__ __forceinline__ int cvtpk(float a, float b) {
  int r;
  asm("v_cvt_pk_bf16_f32 %0, %1, %2" : "=v"(r) : "v"(a), "v"(b));
  return r;
}
// native-range sin/cos: v_sin/v_cos take REVOLUTIONS, fract-reduce first.
__device__ __forceinline__ void fsincos(float ang, float& sn, float& cs) {
  float rev = ang * 0.15915494309189535f;
  rev = rev - floorf(rev);
  float s, c;
  asm("v_sin_f32 %0, %1" : "=v"(s) : "v"(rev));
  asm("v_cos_f32 %0, %1" : "=v"(c) : "v"(rev));
  sn = s; cs = c;
}

// ---------------- cast f32 -> bf16 ----------------
struct CastArgs {
  const float* src[8];
  u16* dst[8];
  int start[8];
};

__global__ __launch_bounds__(256) void cast_kernel(CastArgs a) {
  int blk = blockIdx.x;
  int ti = 0;
#pragma unroll
  for (int i = 1; i < 8; ++i) ti += (blk >= a.start[i]) ? 1 : 0;
  size_t off = (size_t)(blk - a.start[ti]) * 2048 + (size_t)threadIdx.x * 8;
  const float4* s = (const float4*)(a.src[ti] + off);
  float4 v0 = s[0], v1 = s[1];
  u16 o[8];
  o[0] = f2bf(v0.x); o[1] = f2bf(v0.y); o[2] = f2bf(v0.z); o[3] = f2bf(v0.w);
  o[4] = f2bf(v1.x); o[5] = f2bf(v1.y); o[6] = f2bf(v1.z); o[7] = f2bf(v1.w);
  *(short8*)(a.dst[ti] + off) = *(short8*)o;
}

// ---------------- generic B^T GEMM, 2-phase pipelined ----------------
// 8 waves (512 thr), BM=128, BN templated (128 or 256).
struct GemmSeg {
  const u16* A;
  const u16* W;
  const float* bias;
  void* dst;
  int K;
  int mode;
  int ldc;
  float oscale;
};
struct GemmArgs {
  GemmSeg seg[5];
  int nbstart[6];
  int nseg;
};

template <int BN>
__global__ __launch_bounds__(512) void gemm_bt(GemmArgs ga) {
  constexpr int NJ = BN / 64;           // 128->2, 256->4
  constexpr int BUF = 8192 + BN * 64;   // A(8K) + B(BN*32*2)
  __shared__ char glds[2 * BUF];
  const int nb = blockIdx.x, mb = blockIdx.y;
  int si = 0;
  for (int i = 1; i < ga.nseg; ++i) si += (nb >= ga.nbstart[i]) ? 1 : 0;
  GemmSeg sg = ga.seg[si];
  const int nbl = nb - ga.nbstart[si];
  const int K = sg.K;
  const int t = threadIdx.x;
  const int l = t & 63, w = t >> 6;
  const int r0 = t >> 2, c0 = (t & 3) * 8;
  const int wm = (w >> 2) * 64;
  const int wn = (w & 3) * (BN / 4);
  const int frow = l & 15, fk = (l >> 4) * 8;
  const int lafO = ((wm + frow) * 32 + fk) * 2;
  const int lbfO = 8192 + ((wn + frow) * 32 + fk) * 2;

  const u16* apA = sg.A + (size_t)mb * 128 * K + (size_t)r0 * K + c0;
  const u16* wpA = sg.W + (size_t)nbl * BN * K + (size_t)r0 * K + c0;

  auto stage = [&](int bufOff) {
    async16(apA, glds + bufOff + t * 16);
    async16(wpA, glds + bufOff + 8192 + t * 16);
    if constexpr (BN == 256)
      async16(wpA + (size_t)128 * K, glds + bufOff + 16384 + t * 16);
    apA += 32; wpA += 32;
  };

  const f32x4 vzero = {0.f, 0.f, 0.f, 0.f};
  f32x4 acc[4][NJ];
#pragma unroll
  for (int i = 0; i < 4; ++i)
#pragma unroll
    for (int j = 0; j < NJ; ++j) acc[i][j] = vzero;

  stage(0);
  const int nk = K / 32;

  auto ktile = [&](auto bufc, bool stageNext) {
    constexpr int BO = decltype(bufc)::value;
    if (stageNext) {
      stage(BO ^ BUF);
      if constexpr (BN == 256)
        asm volatile("s_waitcnt vmcnt(3)" ::: "memory");
      else
        asm volatile("s_waitcnt vmcnt(2)" ::: "memory");
    } else {
      asm volatile("s_waitcnt vmcnt(0)" ::: "memory");
    }
    __builtin_amdgcn_s_barrier();
    asm volatile("" ::: "memory");
    short8 af[4], bfr[NJ];
#pragma unroll
    for (int i = 0; i < 4; ++i) af[i] = *(const short8*)(glds + BO + lafO + i * 1024);
#pragma unroll
    for (int j = 0; j < NJ; ++j) bfr[j] = *(const short8*)(glds + BO + lbfO + j * 1024);
    __builtin_amdgcn_s_setprio(1);
#pragma unroll
    for (int i = 0; i < 4; ++i)
#pragma unroll
      for (int j = 0; j < NJ; ++j)
        acc[i][j] = __builtin_amdgcn_mfma_f32_16x16x32_bf16(af[i], bfr[j], acc[i][j], 0, 0, 0);
    __builtin_amdgcn_s_setprio(0);
    asm volatile("s_waitcnt lgkmcnt(0)" ::: "memory");
    __builtin_amdgcn_s_barrier();
  };

  for (int kk = 0; kk < nk; kk += 2) {
    ktile(IC<0>{}, true);
    ktile(IC<BUF>{}, kk + 2 < nk);
  }

  const int rb = (l >> 4) * 4;
  const int cl = l & 15;
  const int mode = sg.mode;
  if (mode == 0) {
    u16* D = (u16*)sg.dst;
    float os = sg.oscale;
#pragma unroll
    for (int i = 0; i < 4; ++i)
#pragma unroll
      for (int j = 0; j < NJ; ++j) {
        int col = nbl * BN + wn + j * 16 + cl;
        float bv = sg.bias[col];
#pragma unroll
        for (int r = 0; r < 4; ++r) {
          int row = mb * 128 + wm + i * 16 + rb + r;
          D[(size_t)row * sg.ldc + col] = f2bf((acc[i][j][r] + bv) * os);
        }
      }
  } else if (mode == 2) {
    float* D = (float*)sg.dst;
#pragma unroll
    for (int i = 0; i < 4; ++i)
#pragma unroll
      for (int j = 0; j < NJ; ++j) {
        int col = nbl * BN + wn + j * 16 + cl;
        float bv = sg.bias[col];
#pragma unroll
        for (int r = 0; r < 4; ++r) {
          int row = mb * 128 + wm + i * 16 + rb + r;
          D[(size_t)row * sg.ldc + col] = acc[i][j][r] + bv;
        }
      }
  } else if (mode == 1) {
    // V blocked: Vtb[b][h][s/8][dv][s%8]
    u16* D = (u16*)sg.dst;
#pragma unroll
    for (int i = 0; i < 4; ++i) {
      int row0 = mb * 128 + wm + i * 16 + rb;
      int bb = row0 >> 11, s = row0 & (NS - 1);
#pragma unroll
      for (int j = 0; j < NJ; ++j) {
        int col = nbl * BN + wn + j * 16 + cl;
        int hh = col >> 7, dv = col & 127;
        float bv = sg.bias[col];
        u16 pk[4];
#pragma unroll
        for (int r = 0; r < 4; ++r) pk[r] = f2bf(acc[i][j][r] + bv);
        size_t cell = ((size_t)((bb * NH + hh) * (NS / 8) + (s >> 3)) * 128 + dv) * 8 + (s & 7);
        *(short4v*)(D + cell) = *(short4v*)pk;
      }
    }
  } else if (mode == 4) {
    // k_c -> Ktb[b][h][d/8][s][d%8]
    u16* D = (u16*)sg.dst;
#pragma unroll
    for (int i = 0; i < 4; ++i) {
      int row0 = mb * 128 + wm + i * 16 + rb;
      int bb = row0 >> 11, s = row0 & (NS - 1);
#pragma unroll
      for (int j = 0; j < NJ; ++j) {
        int col = nbl * BN + wn + j * 16 + cl;
        int hh = col >> 7, d = col & 127;
        float bv = sg.bias[col];
        size_t base = ((size_t)((bb * NH + hh) * 24 + (d >> 3)) * NS + s) * 8 + (d & 7);
#pragma unroll
        for (int r = 0; r < 4; ++r) D[base + r * 8] = f2bf(acc[i][j][r] + bv);
      }
    }
  } else if (mode == 5) {
    // k_r -> rope -> Ktb chunk 16+(dr/8)
    u16* D = (u16*)sg.dst;
#pragma unroll
    for (int i = 0; i < 4; ++i) {
      int row0 = mb * 128 + wm + i * 16 + rb;
      int bb = row0 >> 11, s = row0 & (NS - 1);
#pragma unroll
      for (int j = 0; j < NJ; ++j) {
        int col = nbl * BN + wn + j * 16 + cl;
        int hh = col >> 6, dr = col & 63;
        int jp = dr >> 1;
        bool ev = !(dr & 1);
        float invf = exp2f(-(float)jp * 0.41524101186f);
        float bv = sg.bias[col];
        size_t base = ((size_t)((bb * NH + hh) * 24 + 16 + (dr >> 3)) * NS + s) * 8 + (dr & 7);
#pragma unroll
        for (int r = 0; r < 4; ++r) {
          float v = acc[i][j][r] + bv;
          float p = __shfl_xor(v, 1);
          float sn, cs;
          fsincos((float)(s + r) * invf, sn, cs);
          float out = ev ? (v * cs - p * sn) : (p * sn + v * cs);
          D[base + r * 8] = f2bf(out);
        }
      }
    }
  } else {
    // mode 3: q_r -> rope -> bf16 rowmajor, *oscale
    u16* D = (u16*)sg.dst;
    float os = sg.oscale;
#pragma unroll
    for (int i = 0; i < 4; ++i) {
      int row0 = mb * 128 + wm + i * 16 + rb;
      int s = row0 & (NS - 1);
#pragma unroll
      for (int j = 0; j < NJ; ++j) {
        int col = nbl * BN + wn + j * 16 + cl;
        int dr = col & 63;
        int jp = dr >> 1;
        bool ev = !(dr & 1);
        float invf = exp2f(-(float)jp * 0.41524101186f);
        float bv = sg.bias[col];
#pragma unroll
        for (int r = 0; r < 4; ++r) {
          float v = acc[i][j][r] + bv;
          float p = __shfl_xor(v, 1);
          float sn, cs;
          fsincos((float)(s + r) * invf, sn, cs);
          float out = ev ? (v * cs - p * sn) : (p * sn + v * cs);
          D[(size_t)(row0 + r) * sg.ldc + col] = f2bf(out * os);
        }
      }
    }
  }
}

// ---------------- flash attention: single-buffered KV, 4 blocks/CU ----------------
// Identical math to the r9/r14 optimum; the double buffer is dropped so LDS is
// 40960/block -> 4 blocks/CU (16 waves/CU). Per-block load latency is exposed but
// covered by the 3 sibling blocks on the CU.
__global__ __launch_bounds__(256, 2) void attn_kernel(
    const u16* __restrict__ Qc, const u16* __restrict__ Qr,
    const u16* __restrict__ Ktb, const u16* __restrict__ Vtb,
    u16* __restrict__ Ctx) {
  extern __shared__ char smem[];   // 24576 K + 16384 V = 40960
  const int t = threadIdx.x, w = t >> 6, l = t & 63;
  const int hi = l >> 5, q32 = l & 31;
  const int lin = blockIdx.x;
  const int xcd = lin & 7, idx = lin >> 3;
  const int bh = xcd * 4 + (idx >> 4);
  const int qb = idx & 15;
  const int b = bh >> 4, h = bh & 15;
  const int q0 = qb * 128 + w * 32;

  short8 qf[12];
  {
    const u16* qcp = Qc + ((size_t)(b * NS + q0 + q32)) * NHID + h * NDH + hi * 8;
    const u16* qrp = Qr + ((size_t)(b * NS + q0 + q32)) * (NH * NDR) + h * NDR + hi * 8;
#pragma unroll
    for (int dw = 0; dw < 8; ++dw) qf[dw] = *(const short8*)(qcp + dw * 16);
#pragma unroll
    for (int dw = 0; dw < 4; ++dw) qf[8 + dw] = *(const short8*)(qrp + dw * 16);
  }
#pragma unroll
  for (int dw = 0; dw < 12; ++dw) asm volatile("" :: "v"(qf[dw]));

  const int w2 = t >> 6;
  const u16* kp[6];
#pragma unroll
  for (int r = 0; r < 6; ++r)
    kp[r] = Ktb + ((size_t)(bh * 24 + r * 4 + w2) * NS + l) * 8;
  const u16* vp = Vtb + (size_t)bh * NS * 128 + t * 8;

  const int kbase = q32 * 16 + hi * 1024;
  const int vbase = 24576 + q32 * 16 + hi * 2048;

  f32x16 acc[4], accS, fz;
#pragma unroll
  for (int r = 0; r < 16; ++r) { fz[r] = 0.f; accS[r] = 0.f; }
#pragma unroll
  for (int i = 0; i < 4; ++i) acc[i] = fz;
  union { int i[4]; short8 s; } ONES;
  ONES.i[0] = 0x3F803F80; ONES.i[1] = 0x3F803F80;
  ONES.i[2] = 0x3F803F80; ONES.i[3] = 0x3F803F80;

  auto stage_into = [&]() {
#pragma unroll
    for (int r = 0; r < 6; ++r) { async16(kp[r], smem + r * 4096 + t * 16); kp[r] += 512; }
#pragma unroll
    for (int r = 0; r < 4; ++r) async16(vp + r * 2048, smem + 24576 + r * 4096 + t * 16);
    vp += 8192;
  };
  stage_into();

  // PV for one 32-key score block: exp fused, denominator via ones-MFMA
  auto pv_block = [&](const f32x16& s, int n, const char* vb) {
#pragma unroll
    for (int w2i = 0; w2i < 2; ++w2i) {
      const int bse = w2i * 8;
      float p0 = exp2f(s[bse + 0]), p1 = exp2f(s[bse + 1]);
      float p2 = exp2f(s[bse + 2]), p3 = exp2f(s[bse + 3]);
      float p4 = exp2f(s[bse + 4]), p5 = exp2f(s[bse + 5]);
      float p6 = exp2f(s[bse + 6]), p7 = exp2f(s[bse + 7]);
      int A0 = cvtpk(p0, p1);
      int A1 = cvtpk(p2, p3);
      int B0 = cvtpk(p4, p5);
      int B1 = cvtpk(p6, p7);
      int2v r02 = __builtin_amdgcn_permlane32_swap(A0, B0, false, false);
      int2v r13 = __builtin_amdgcn_permlane32_swap(A1, B1, false, false);
      union { int i[4]; short8 s; } F;
      F.i[0] = r02[0]; F.i[1] = r13[0]; F.i[2] = r02[1]; F.i[3] = r13[1];
      const int W = n * 2 + w2i;
      __builtin_amdgcn_s_setprio(1);
#pragma unroll
      for (int d32 = 0; d32 < 4; ++d32) {
        short8 va = *(const short8*)(vb + W * 4096 + d32 * 512);
        acc[d32] = __builtin_amdgcn_mfma_f32_32x32x16_bf16(va, F.s, acc[d32], 0, 0, 0);
      }
      accS = __builtin_amdgcn_mfma_f32_32x32x16_bf16(ONES.s, F.s, accS, 0, 0, 0);
      __builtin_amdgcn_s_setprio(0);
    }
  };

  for (int kv = 0; kv < NS / 64; ++kv) {
    asm volatile("s_waitcnt vmcnt(0)" ::: "memory");
    __builtin_amdgcn_s_barrier();
    asm volatile("" ::: "memory");

    f32x16 sa0, sa1;
    {
      short8 k0 = *(const short8*)(smem + kbase);
      short8 k1 = *(const short8*)(smem + kbase + 512);
      __builtin_amdgcn_s_setprio(1);
      sa0 = __builtin_amdgcn_mfma_f32_32x32x16_bf16(k0, qf[0], fz, 0, 0, 0);
      sa1 = __builtin_amdgcn_mfma_f32_32x32x16_bf16(k1, qf[0], fz, 0, 0, 0);
      __builtin_amdgcn_s_setprio(0);
    }
#pragma unroll
    for (int dw = 1; dw < 12; ++dw) {
      short8 k0 = *(const short8*)(smem + kbase + dw * 2048);
      short8 k1 = *(const short8*)(smem + kbase + dw * 2048 + 512);
      __builtin_amdgcn_s_setprio(1);
      sa0 = __builtin_amdgcn_mfma_f32_32x32x16_bf16(k0, qf[dw], sa0, 0, 0, 0);
      sa1 = __builtin_amdgcn_mfma_f32_32x32x16_bf16(k1, qf[dw], sa1, 0, 0, 0);
      __builtin_amdgcn_s_setprio(0);
    }

    const char* vb = (const char*)smem + vbase;
    pv_block(sa0, 0, vb);
    pv_block(sa1, 1, vb);

    asm volatile("s_waitcnt lgkmcnt(0)" ::: "memory");
    __builtin_amdgcn_s_barrier();
    if (kv + 1 < NS / 64) stage_into();
  }

  float invq = 1.f / accS[0];
  u16* dst = Ctx + ((size_t)(b * NS + q0 + q32)) * NHID + h * NDH + hi * 4;
#pragma unroll
  for (int d32 = 0; d32 < 4; ++d32)
#pragma unroll
    for (int m2x = 0; m2x < 4; ++m2x) {
      float a0 = acc[d32][m2x * 4 + 0] * invq, a1 = acc[d32][m2x * 4 + 1] * invq;
      float a2 = acc[d32][m2x * 4 + 2] * invq, a3 = acc[d32][m2x * 4 + 3] * invq;
      union { int i[2]; short4v s; } pu;
      pu.i[0] = cvtpk(a0, a1);
      pu.i[1] = cvtpk(a2, a3);
      *(short4v*)(dst + d32 * 32 + m2x * 8) = pu.s;
    }
}

// ---------------- host ----------------
extern "C" void kernel_launch(void* const* d_in, const int* in_sizes, int n_in,
                              void* d_out, int out_size, void* d_ws, size_t ws_size,
                              hipStream_t stream) {
  (void)in_sizes; (void)n_in; (void)out_size;
  const float* x      = (const float*)d_in[0];
  const float* d_kv_w = (const float*)d_in[1];
  const float* d_kv_b = (const float*)d_in[2];
  const float* u_k_w  = (const float*)d_in[3];
  const float* u_k_b  = (const float*)d_in[4];
  const float* u_v_w  = (const float*)d_in[5];
  const float* u_v_b  = (const float*)d_in[6];
  const float* d_q_w  = (const float*)d_in[7];
  const float* d_q_b  = (const float*)d_in[8];
  const float* u_q_w  = (const float*)d_in[9];
  const float* u_q_b  = (const float*)d_in[10];
  const float* qr_w   = (const float*)d_in[11];
  const float* qr_b   = (const float*)d_in[12];
  const float* out_w  = (const float*)d_in[13];
  const float* out_b  = (const float*)d_in[14];

  char* ws = (char*)d_ws;
  size_t off = 0;
  auto alloc = [&](size_t bytes) -> void* {
    void* p = ws + off;
    off += (bytes + 255) & ~(size_t)255;
    return p;
  };
  u16* xb   = (u16*)alloc((size_t)NB * NS * NHID * 2);
  u16* wdkv = (u16*)alloc((size_t)NC * NHID * 2);
  u16* wuk  = (u16*)alloc((size_t)NH * NDH * NC * 2);
  u16* wuv  = (u16*)alloc((size_t)NH * NDH * NC * 2);
  u16* wdq  = (u16*)alloc((size_t)NC * NHID * 2);
  u16* wuq  = (u16*)alloc((size_t)NH * NDH * NC * 2);
  u16* wqr  = (u16*)alloc((size_t)NH * NDR * NC * 2);
  u16* wout = (u16*)alloc((size_t)NHID * NH * NDH * 2);
  u16* kvc  = (u16*)alloc((size_t)NB * NS * NC * 2);
  u16* qlat = (u16*)alloc((size_t)NB * NS * NC * 2);
  u16* Ktb  = (u16*)alloc((size_t)NB * NH * 24 * NS * 8 * 2);
  u16* Vtb  = (u16*)alloc((size_t)NB * NH * NS * NDH * 2);
  u16* Qc   = (u16*)alloc((size_t)NB * NS * NH * NDH * 2);
  u16* Qrt  = (u16*)alloc((size_t)NB * NS * NH * NDR * 2);
  u16* ctx  = xb;  // alias: x (bf16) dead after latent GEMM
  if (off > ws_size) return;

  // 1) cast
  {
    CastArgs ca;
    const float* srcs[8] = {x, d_kv_w, u_k_w, u_v_w, d_q_w, u_q_w, qr_w, out_w};
    u16* dsts[8] = {xb, wdkv, wuk, wuv, wdq, wuq, wqr, wout};
    int sizes[8] = {NB * NS * NHID, NC * NHID, NH * NDH * NC, NH * NDH * NC,
                    NC * NHID, NH * NDH * NC, NH * NDR * NC, NHID * NH * NDH};
    int st = 0;
    for (int i = 0; i < 8; ++i) {
      ca.src[i] = srcs[i]; ca.dst[i] = dsts[i]; ca.start[i] = st;
      st += sizes[i] / 2048;
    }
    cast_kernel<<<dim3(st), dim3(256), 0, stream>>>(ca);
  }

  // 2) latent GEMM (K=2048, BN=128)
  {
    GemmArgs ga;
    ga.nseg = 2;
    ga.seg[0] = {xb, wdkv, d_kv_b, kvc, NHID, 0, NC, 1.f};
    ga.seg[1] = {xb, wdq,  d_q_b,  qlat, NHID, 0, NC, 1.f};
    for (int i = 2; i < 5; ++i) ga.seg[i] = ga.seg[0];
    ga.nbstart[0] = 0; ga.nbstart[1] = 4; ga.nbstart[2] = 8;
    ga.nbstart[3] = 8; ga.nbstart[4] = 8; ga.nbstart[5] = 8;
    gemm_bt<128><<<dim3(8, 32), dim3(512), 0, stream>>>(ga);
  }

  // 3) up GEMMs (K=512, BN=256): k_c->Ktb, v->Vtb, k_r->rope->Ktb, q_c*SC2, q_r->rope*SC2
  {
    GemmArgs ga;
    ga.nseg = 5;
    ga.seg[0] = {kvc,  wuk, u_k_b, Ktb, NC, 4, 0, 1.f};
    ga.seg[1] = {kvc,  wuv, u_v_b, Vtb, NC, 1, 0, 1.f};
    ga.seg[2] = {kvc,  wqr, qr_b,  Ktb, NC, 5, 0, 1.f};
    ga.seg[3] = {qlat, wuq, u_q_b, Qc,  NC, 0, NH * NDH, SC2};
    ga.seg[4] = {qlat, wqr, qr_b,  Qrt, NC, 3, NH * NDR, SC2};
    ga.nbstart[0] = 0;  ga.nbstart[1] = 8;  ga.nbstart[2] = 16;
    ga.nbstart[3] = 20; ga.nbstart[4] = 28; ga.nbstart[5] = 32;
    gemm_bt<256><<<dim3(32, 32), dim3(512), 0, stream>>>(ga);
  }

  // 4) attention (40KB dynamic LDS, 4 blocks/CU)
  hipFuncSetAttribute((const void*)attn_kernel,
                      hipFuncAttributeMaxDynamicSharedMemorySize, 40960);
  attn_kernel<<<dim3(512), dim3(256), 40960, stream>>>(Qc, Qrt, Ktb, Vtb, ctx);

  // 5) out projection (f32 out + bias, BN=256)
  {
    GemmArgs ga;
    ga.nseg = 1;
    ga.seg[0] = {ctx, wout, out_b, d_out, NHID, 2, NHID, 1.f};
    for (int i = 1; i < 5; ++i) ga.seg[i] = ga.seg[0];
    ga.nbstart[0] = 0;
    for (int i = 1; i < 6; ++i) ga.nbstart[i] = 8;
    gemm_bt<256><<<dim3(8, 32), dim3(512), 0, stream>>>(ga);
  }
}

// Round 16
// 253.711 us; speedup vs baseline: 1.0104x; 1.0104x over previous
//
#include <hip/hip_runtime.h>
#include <hip/hip_bf16.h>
#include <math.h>
#include <stdint.h>

#define NB 2
#define NS 2048
#define NH 16
#define NDH 128
#define NDR 64
#define NHID 2048
#define NC 512

typedef unsigned short u16;
typedef short short8 __attribute__((ext_vector_type(8)));
typedef short short4v __attribute__((ext_vector_type(4)));
typedef float f32x4 __attribute__((ext_vector_type(4)));
typedef float f32x16 __attribute__((ext_vector_type(16)));
typedef int int2v __attribute__((ext_vector_type(2)));

#define SC2 0.10411757f   /* (1/sqrt(192)) * log2(e) */

template <int V> struct IC { static constexpr int value = V; };

__device__ __forceinline__ u16 f2bf(float f) {
  union { float f; uint32_t u; } c; c.f = f;
  uint32_t u = c.u + 0x7fffu + ((c.u >> 16) & 1u);
  return (u16)(u >> 16);
}
__device__ __forceinline__ void async16(const void* g, void* l) {
  __builtin_amdgcn_global_load_lds((const __attribute__((address_space(1))) void*)g,
                                   (__attribute__((address_space(3))) void*)l, 16, 0, 0);
}
__device__ __forceinline__ int cvtpk(float a, float b) {
  int r;
  asm("v_cvt_pk_bf16_f32 %0, %1, %2" : "=v"(r) : "v"(a), "v"(b));
  return r;
}
// native-range sin/cos: v_sin/v_cos take REVOLUTIONS, fract-reduce first.
__device__ __forceinline__ void fsincos(float ang, float& sn, float& cs) {
  float rev = ang * 0.15915494309189535f;
  rev = rev - floorf(rev);
  float s, c;
  asm("v_sin_f32 %0, %1" : "=v"(s) : "v"(rev));
  asm("v_cos_f32 %0, %1" : "=v"(c) : "v"(rev));
  sn = s; cs = c;
}

// ---------------- cast f32 -> bf16 ----------------
struct CastArgs {
  const float* src[8];
  u16* dst[8];
  int start[8];
};

__global__ __launch_bounds__(256) void cast_kernel(CastArgs a) {
  int blk = blockIdx.x;
  int ti = 0;
#pragma unroll
  for (int i = 1; i < 8; ++i) ti += (blk >= a.start[i]) ? 1 : 0;
  size_t off = (size_t)(blk - a.start[ti]) * 2048 + (size_t)threadIdx.x * 8;
  const float4* s = (const float4*)(a.src[ti] + off);
  float4 v0 = s[0], v1 = s[1];
  u16 o[8];
  o[0] = f2bf(v0.x); o[1] = f2bf(v0.y); o[2] = f2bf(v0.z); o[3] = f2bf(v0.w);
  o[4] = f2bf(v1.x); o[5] = f2bf(v1.y); o[6] = f2bf(v1.z); o[7] = f2bf(v1.w);
  *(short8*)(a.dst[ti] + off) = *(short8*)o;
}

// ---------------- generic B^T GEMM, 2-phase pipelined ----------------
// 8 waves (512 thr), BM=128, BN templated (128 or 256).
// XCD-aware bijective block swizzle (total blocks % 8 == 0 for all launches):
// each XCD gets a contiguous nb chunk so W-panel reuse is L2-local.
struct GemmSeg {
  const u16* A;
  const u16* W;
  const float* bias;
  void* dst;
  int K;
  int mode;
  int ldc;
  float oscale;
};
struct GemmArgs {
  GemmSeg seg[5];
  int nbstart[6];
  int nseg;
};

template <int BN>
__global__ __launch_bounds__(512) void gemm_bt(GemmArgs ga) {
  constexpr int NJ = BN / 64;           // 128->2, 256->4
  constexpr int BUF = 8192 + BN * 64;   // A(8K) + B(BN*32*2)
  __shared__ char glds[2 * BUF];
  // XCD swizzle: lin dispatch order is x-fastest; remap so each XCD owns a
  // contiguous swz chunk, decomposed nb-major (contiguous nb per XCD).
  const int GX = gridDim.x, GY = gridDim.y;
  const int lin = blockIdx.y * GX + blockIdx.x;
  const int chunk = (GX * GY) >> 3;
  const int swz = (lin & 7) * chunk + (lin >> 3);
  const int nb = swz / GY, mb = swz % GY;
  int si = 0;
  for (int i = 1; i < ga.nseg; ++i) si += (nb >= ga.nbstart[i]) ? 1 : 0;
  GemmSeg sg = ga.seg[si];
  const int nbl = nb - ga.nbstart[si];
  const int K = sg.K;
  const int t = threadIdx.x;
  const int l = t & 63, w = t >> 6;
  const int r0 = t >> 2, c0 = (t & 3) * 8;
  const int wm = (w >> 2) * 64;
  const int wn = (w & 3) * (BN / 4);
  const int frow = l & 15, fk = (l >> 4) * 8;
  const int lafO = ((wm + frow) * 32 + fk) * 2;
  const int lbfO = 8192 + ((wn + frow) * 32 + fk) * 2;

  const u16* apA = sg.A + (size_t)mb * 128 * K + (size_t)r0 * K + c0;
  const u16* wpA = sg.W + (size_t)nbl * BN * K + (size_t)r0 * K + c0;

  auto stage = [&](int bufOff) {
    async16(apA, glds + bufOff + t * 16);
    async16(wpA, glds + bufOff + 8192 + t * 16);
    if constexpr (BN == 256)
      async16(wpA + (size_t)128 * K, glds + bufOff + 16384 + t * 16);
    apA += 32; wpA += 32;
  };

  const f32x4 vzero = {0.f, 0.f, 0.f, 0.f};
  f32x4 acc[4][NJ];
#pragma unroll
  for (int i = 0; i < 4; ++i)
#pragma unroll
    for (int j = 0; j < NJ; ++j) acc[i][j] = vzero;

  stage(0);
  const int nk = K / 32;

  auto ktile = [&](auto bufc, bool stageNext) {
    constexpr int BO = decltype(bufc)::value;
    if (stageNext) {
      stage(BO ^ BUF);
      if constexpr (BN == 256)
        asm volatile("s_waitcnt vmcnt(3)" ::: "memory");
      else
        asm volatile("s_waitcnt vmcnt(2)" ::: "memory");
    } else {
      asm volatile("s_waitcnt vmcnt(0)" ::: "memory");
    }
    __builtin_amdgcn_s_barrier();
    asm volatile("" ::: "memory");
    short8 af[4], bfr[NJ];
#pragma unroll
    for (int i = 0; i < 4; ++i) af[i] = *(const short8*)(glds + BO + lafO + i * 1024);
#pragma unroll
    for (int j = 0; j < NJ; ++j) bfr[j] = *(const short8*)(glds + BO + lbfO + j * 1024);
    __builtin_amdgcn_s_setprio(1);
#pragma unroll
    for (int i = 0; i < 4; ++i)
#pragma unroll
      for (int j = 0; j < NJ; ++j)
        acc[i][j] = __builtin_amdgcn_mfma_f32_16x16x32_bf16(af[i], bfr[j], acc[i][j], 0, 0, 0);
    __builtin_amdgcn_s_setprio(0);
    asm volatile("s_waitcnt lgkmcnt(0)" ::: "memory");
    __builtin_amdgcn_s_barrier();
  };

  for (int kk = 0; kk < nk; kk += 2) {
    ktile(IC<0>{}, true);
    ktile(IC<BUF>{}, kk + 2 < nk);
  }

  const int rb = (l >> 4) * 4;
  const int cl = l & 15;
  const int mode = sg.mode;
  if (mode == 0) {
    u16* D = (u16*)sg.dst;
    float os = sg.oscale;
#pragma unroll
    for (int i = 0; i < 4; ++i)
#pragma unroll
      for (int j = 0; j < NJ; ++j) {
        int col = nbl * BN + wn + j * 16 + cl;
        float bv = sg.bias[col];
#pragma unroll
        for (int r = 0; r < 4; ++r) {
          int row = mb * 128 + wm + i * 16 + rb + r;
          D[(size_t)row * sg.ldc + col] = f2bf((acc[i][j][r] + bv) * os);
        }
      }
  } else if (mode == 2) {
    float* D = (float*)sg.dst;
#pragma unroll
    for (int i = 0; i < 4; ++i)
#pragma unroll
      for (int j = 0; j < NJ; ++j) {
        int col = nbl * BN + wn + j * 16 + cl;
        float bv = sg.bias[col];
#pragma unroll
        for (int r = 0; r < 4; ++r) {
          int row = mb * 128 + wm + i * 16 + rb + r;
          D[(size_t)row * sg.ldc + col] = acc[i][j][r] + bv;
        }
      }
  } else if (mode == 1) {
    // V blocked: Vtb[b][h][s/8][dv][s%8]
    u16* D = (u16*)sg.dst;
#pragma unroll
    for (int i = 0; i < 4; ++i) {
      int row0 = mb * 128 + wm + i * 16 + rb;
      int bb = row0 >> 11, s = row0 & (NS - 1);
#pragma unroll
      for (int j = 0; j < NJ; ++j) {
        int col = nbl * BN + wn + j * 16 + cl;
        int hh = col >> 7, dv = col & 127;
        float bv = sg.bias[col];
        u16 pk[4];
#pragma unroll
        for (int r = 0; r < 4; ++r) pk[r] = f2bf(acc[i][j][r] + bv);
        size_t cell = ((size_t)((bb * NH + hh) * (NS / 8) + (s >> 3)) * 128 + dv) * 8 + (s & 7);
        *(short4v*)(D + cell) = *(short4v*)pk;
      }
    }
  } else if (mode == 4) {
    // k_c -> Ktb[b][h][d/8][s][d%8]
    u16* D = (u16*)sg.dst;
#pragma unroll
    for (int i = 0; i < 4; ++i) {
      int row0 = mb * 128 + wm + i * 16 + rb;
      int bb = row0 >> 11, s = row0 & (NS - 1);
#pragma unroll
      for (int j = 0; j < NJ; ++j) {
        int col = nbl * BN + wn + j * 16 + cl;
        int hh = col >> 7, d = col & 127;
        float bv = sg.bias[col];
        size_t base = ((size_t)((bb * NH + hh) * 24 + (d >> 3)) * NS + s) * 8 + (d & 7);
#pragma unroll
        for (int r = 0; r < 4; ++r) D[base + r * 8] = f2bf(acc[i][j][r] + bv);
      }
    }
  } else if (mode == 5) {
    // k_r -> rope -> Ktb chunk 16+(dr/8)
    u16* D = (u16*)sg.dst;
#pragma unroll
    for (int i = 0; i < 4; ++i) {
      int row0 = mb * 128 + wm + i * 16 + rb;
      int bb = row0 >> 11, s = row0 & (NS - 1);
#pragma unroll
      for (int j = 0; j < NJ; ++j) {
        int col = nbl * BN + wn + j * 16 + cl;
        int hh = col >> 6, dr = col & 63;
        int jp = dr >> 1;
        bool ev = !(dr & 1);
        float invf = exp2f(-(float)jp * 0.41524101186f);
        float bv = sg.bias[col];
        size_t base = ((size_t)((bb * NH + hh) * 24 + 16 + (dr >> 3)) * NS + s) * 8 + (dr & 7);
#pragma unroll
        for (int r = 0; r < 4; ++r) {
          float v = acc[i][j][r] + bv;
          float p = __shfl_xor(v, 1);
          float sn, cs;
          fsincos((float)(s + r) * invf, sn, cs);
          float out = ev ? (v * cs - p * sn) : (p * sn + v * cs);
          D[base + r * 8] = f2bf(out);
        }
      }
    }
  } else {
    // mode 3: q_r -> rope -> bf16 rowmajor, *oscale
    u16* D = (u16*)sg.dst;
    float os = sg.oscale;
#pragma unroll
    for (int i = 0; i < 4; ++i) {
      int row0 = mb * 128 + wm + i * 16 + rb;
      int s = row0 & (NS - 1);
#pragma unroll
      for (int j = 0; j < NJ; ++j) {
        int col = nbl * BN + wn + j * 16 + cl;
        int dr = col & 63;
        int jp = dr >> 1;
        bool ev = !(dr & 1);
        float invf = exp2f(-(float)jp * 0.41524101186f);
        float bv = sg.bias[col];
#pragma unroll
        for (int r = 0; r < 4; ++r) {
          float v = acc[i][j][r] + bv;
          float p = __shfl_xor(v, 1);
          float sn, cs;
          fsincos((float)(s + r) * invf, sn, cs);
          float out = ev ? (v * cs - p * sn) : (p * sn + v * cs);
          D[(size_t)(row0 + r) * sg.ldc + col] = f2bf(out * os);
        }
      }
    }
  }
}

// ---------------- flash attention (round-9/14 optimum) ----------------
// Q pre-scaled by SC2 at GEMM epilogue; shift-free softmax p = exp2(s).
// Zero-init via hoisted fz C-operand; row-sum via ones-MFMA (matrix pipe).
__global__ __launch_bounds__(256, 2) void attn_kernel(
    const u16* __restrict__ Qc, const u16* __restrict__ Qr,
    const u16* __restrict__ Ktb, const u16* __restrict__ Vtb,
    u16* __restrict__ Ctx) {
  extern __shared__ char smem[];   // 2 x (24576 K + 16384 V) = 81920
  const int t = threadIdx.x, w = t >> 6, l = t & 63;
  const int hi = l >> 5, q32 = l & 31;
  const int lin = blockIdx.x;
  const int xcd = lin & 7, idx = lin >> 3;
  const int bh = xcd * 4 + (idx >> 4);
  const int qb = idx & 15;
  const int b = bh >> 4, h = bh & 15;
  const int q0 = qb * 128 + w * 32;

  short8 qf[12];
  {
    const u16* qcp = Qc + ((size_t)(b * NS + q0 + q32)) * NHID + h * NDH + hi * 8;
    const u16* qrp = Qr + ((size_t)(b * NS + q0 + q32)) * (NH * NDR) + h * NDR + hi * 8;
#pragma unroll
    for (int dw = 0; dw < 8; ++dw) qf[dw] = *(const short8*)(qcp + dw * 16);
#pragma unroll
    for (int dw = 0; dw < 4; ++dw) qf[8 + dw] = *(const short8*)(qrp + dw * 16);
  }
#pragma unroll
  for (int dw = 0; dw < 12; ++dw) asm volatile("" :: "v"(qf[dw]));

  const int w2 = t >> 6;
  const u16* kp[6];
#pragma unroll
  for (int r = 0; r < 6; ++r)
    kp[r] = Ktb + ((size_t)(bh * 24 + r * 4 + w2) * NS + l) * 8;
  const u16* vp = Vtb + (size_t)bh * NS * 128 + t * 8;

  const int kbase = q32 * 16 + hi * 1024;
  const int vbase = 24576 + q32 * 16 + hi * 2048;

  f32x16 acc[4], accS, fz;
#pragma unroll
  for (int r = 0; r < 16; ++r) { fz[r] = 0.f; accS[r] = 0.f; }
#pragma unroll
  for (int i = 0; i < 4; ++i) acc[i] = fz;
  union { int i[4]; short8 s; } ONES;
  ONES.i[0] = 0x3F803F80; ONES.i[1] = 0x3F803F80;
  ONES.i[2] = 0x3F803F80; ONES.i[3] = 0x3F803F80;

  auto stage_into = [&](int bufOff) {
#pragma unroll
    for (int r = 0; r < 6; ++r) { async16(kp[r], smem + bufOff + r * 4096 + t * 16); kp[r] += 512; }
#pragma unroll
    for (int r = 0; r < 4; ++r) async16(vp + r * 2048, smem + bufOff + 24576 + r * 4096 + t * 16);
    vp += 8192;
  };
  stage_into(0);

  // PV for one 32-key score block: exp fused, denominator via ones-MFMA
  auto pv_block = [&](const f32x16& s, int n, const char* vb) {
#pragma unroll
    for (int w2i = 0; w2i < 2; ++w2i) {
      const int bse = w2i * 8;
      float p0 = exp2f(s[bse + 0]), p1 = exp2f(s[bse + 1]);
      float p2 = exp2f(s[bse + 2]), p3 = exp2f(s[bse + 3]);
      float p4 = exp2f(s[bse + 4]), p5 = exp2f(s[bse + 5]);
      float p6 = exp2f(s[bse + 6]), p7 = exp2f(s[bse + 7]);
      int A0 = cvtpk(p0, p1);
      int A1 = cvtpk(p2, p3);
      int B0 = cvtpk(p4, p5);
      int B1 = cvtpk(p6, p7);
      int2v r02 = __builtin_amdgcn_permlane32_swap(A0, B0, false, false);
      int2v r13 = __builtin_amdgcn_permlane32_swap(A1, B1, false, false);
      union { int i[4]; short8 s; } F;
      F.i[0] = r02[0]; F.i[1] = r13[0]; F.i[2] = r02[1]; F.i[3] = r13[1];
      const int W = n * 2 + w2i;
      __builtin_amdgcn_s_setprio(1);
#pragma unroll
      for (int d32 = 0; d32 < 4; ++d32) {
        short8 va = *(const short8*)(vb + W * 4096 + d32 * 512);
        acc[d32] = __builtin_amdgcn_mfma_f32_32x32x16_bf16(va, F.s, acc[d32], 0, 0, 0);
      }
      accS = __builtin_amdgcn_mfma_f32_32x32x16_bf16(ONES.s, F.s, accS, 0, 0, 0);
      __builtin_amdgcn_s_setprio(0);
    }
  };

  auto tile = [&](auto bufc, bool stageNext) {
    constexpr int BO = decltype(bufc)::value;
    if (stageNext) {
      stage_into(BO ^ 40960);
      asm volatile("s_waitcnt vmcnt(10)" ::: "memory");
    } else {
      asm volatile("s_waitcnt vmcnt(0)" ::: "memory");
    }
    __builtin_amdgcn_s_barrier();
    asm volatile("" ::: "memory");

    f32x16 sa0, sa1;
    {
      short8 k0 = *(const short8*)(smem + BO + kbase);
      short8 k1 = *(const short8*)(smem + BO + kbase + 512);
      __builtin_amdgcn_s_setprio(1);
      sa0 = __builtin_amdgcn_mfma_f32_32x32x16_bf16(k0, qf[0], fz, 0, 0, 0);
      sa1 = __builtin_amdgcn_mfma_f32_32x32x16_bf16(k1, qf[0], fz, 0, 0, 0);
      __builtin_amdgcn_s_setprio(0);
    }
#pragma unroll
    for (int dw = 1; dw < 12; ++dw) {
      short8 k0 = *(const short8*)(smem + BO + kbase + dw * 2048);
      short8 k1 = *(const short8*)(smem + BO + kbase + dw * 2048 + 512);
      __builtin_amdgcn_s_setprio(1);
      sa0 = __builtin_amdgcn_mfma_f32_32x32x16_bf16(k0, qf[dw], sa0, 0, 0, 0);
      sa1 = __builtin_amdgcn_mfma_f32_32x32x16_bf16(k1, qf[dw], sa1, 0, 0, 0);
      __builtin_amdgcn_s_setprio(0);
    }

    const char* vb = (const char*)smem + BO + vbase;
    pv_block(sa0, 0, vb);
    pv_block(sa1, 1, vb);

    asm volatile("s_waitcnt lgkmcnt(0)" ::: "memory");
    __builtin_amdgcn_s_barrier();
  };

  for (int kv = 0; kv < NS / 64; kv += 2) {
    tile(IC<0>{}, true);
    tile(IC<40960>{}, kv + 2 < NS / 64);
  }

  float invq = 1.f / accS[0];
  u16* dst = Ctx + ((size_t)(b * NS + q0 + q32)) * NHID + h * NDH + hi * 4;
#pragma unroll
  for (int d32 = 0; d32 < 4; ++d32)
#pragma unroll
    for (int m2x = 0; m2x < 4; ++m2x) {
      float a0 = acc[d32][m2x * 4 + 0] * invq, a1 = acc[d32][m2x * 4 + 1] * invq;
      float a2 = acc[d32][m2x * 4 + 2] * invq, a3 = acc[d32][m2x * 4 + 3] * invq;
      union { int i[2]; short4v s; } pu;
      pu.i[0] = cvtpk(a0, a1);
      pu.i[1] = cvtpk(a2, a3);
      *(short4v*)(dst + d32 * 32 + m2x * 8) = pu.s;
    }
}

// ---------------- host ----------------
extern "C" void kernel_launch(void* const* d_in, const int* in_sizes, int n_in,
                              void* d_out, int out_size, void* d_ws, size_t ws_size,
                              hipStream_t stream) {
  (void)in_sizes; (void)n_in; (void)out_size;
  const float* x      = (const float*)d_in[0];
  const float* d_kv_w = (const float*)d_in[1];
  const float* d_kv_b = (const float*)d_in[2];
  const float* u_k_w  = (const float*)d_in[3];
  const float* u_k_b  = (const float*)d_in[4];
  const float* u_v_w  = (const float*)d_in[5];
  const float* u_v_b  = (const float*)d_in[6];
  const float* d_q_w  = (const float*)d_in[7];
  const float* d_q_b  = (const float*)d_in[8];
  const float* u_q_w  = (const float*)d_in[9];
  const float* u_q_b  = (const float*)d_in[10];
  const float* qr_w   = (const float*)d_in[11];
  const float* qr_b   = (const float*)d_in[12];
  const float* out_w  = (const float*)d_in[13];
  const float* out_b  = (const float*)d_in[14];

  char* ws = (char*)d_ws;
  size_t off = 0;
  auto alloc = [&](size_t bytes) -> void* {
    void* p = ws + off;
    off += (bytes + 255) & ~(size_t)255;
    return p;
  };
  u16* xb   = (u16*)alloc((size_t)NB * NS * NHID * 2);
  u16* wdkv = (u16*)alloc((size_t)NC * NHID * 2);
  u16* wuk  = (u16*)alloc((size_t)NH * NDH * NC * 2);
  u16* wuv  = (u16*)alloc((size_t)NH * NDH * NC * 2);
  u16* wdq  = (u16*)alloc((size_t)NC * NHID * 2);
  u16* wuq  = (u16*)alloc((size_t)NH * NDH * NC * 2);
  u16* wqr  = (u16*)alloc((size_t)NH * NDR * NC * 2);
  u16* wout = (u16*)alloc((size_t)NHID * NH * NDH * 2);
  u16* kvc  = (u16*)alloc((size_t)NB * NS * NC * 2);
  u16* qlat = (u16*)alloc((size_t)NB * NS * NC * 2);
  u16* Ktb  = (u16*)alloc((size_t)NB * NH * 24 * NS * 8 * 2);
  u16* Vtb  = (u16*)alloc((size_t)NB * NH * NS * NDH * 2);
  u16* Qc   = (u16*)alloc((size_t)NB * NS * NH * NDH * 2);
  u16* Qrt  = (u16*)alloc((size_t)NB * NS * NH * NDR * 2);
  u16* ctx  = xb;  // alias: x (bf16) dead after latent GEMM
  if (off > ws_size) return;

  // 1) cast
  {
    CastArgs ca;
    const float* srcs[8] = {x, d_kv_w, u_k_w, u_v_w, d_q_w, u_q_w, qr_w, out_w};
    u16* dsts[8] = {xb, wdkv, wuk, wuv, wdq, wuq, wqr, wout};
    int sizes[8] = {NB * NS * NHID, NC * NHID, NH * NDH * NC, NH * NDH * NC,
                    NC * NHID, NH * NDH * NC, NH * NDR * NC, NHID * NH * NDH};
    int st = 0;
    for (int i = 0; i < 8; ++i) {
      ca.src[i] = srcs[i]; ca.dst[i] = dsts[i]; ca.start[i] = st;
      st += sizes[i] / 2048;
    }
    cast_kernel<<<dim3(st), dim3(256), 0, stream>>>(ca);
  }

  // 2) latent GEMM (K=2048, BN=128)
  {
    GemmArgs ga;
    ga.nseg = 2;
    ga.seg[0] = {xb, wdkv, d_kv_b, kvc, NHID, 0, NC, 1.f};
    ga.seg[1] = {xb, wdq,  d_q_b,  qlat, NHID, 0, NC, 1.f};
    for (int i = 2; i < 5; ++i) ga.seg[i] = ga.seg[0];
    ga.nbstart[0] = 0; ga.nbstart[1] = 4; ga.nbstart[2] = 8;
    ga.nbstart[3] = 8; ga.nbstart[4] = 8; ga.nbstart[5] = 8;
    gemm_bt<128><<<dim3(8, 32), dim3(512), 0, stream>>>(ga);
  }

  // 3) up GEMMs (K=512, BN=256): k_c->Ktb, v->Vtb, k_r->rope->Ktb, q_c*SC2, q_r->rope*SC2
  {
    GemmArgs ga;
    ga.nseg = 5;
    ga.seg[0] = {kvc,  wuk, u_k_b, Ktb, NC, 4, 0, 1.f};
    ga.seg[1] = {kvc,  wuv, u_v_b, Vtb, NC, 1, 0, 1.f};
    ga.seg[2] = {kvc,  wqr, qr_b,  Ktb, NC, 5, 0, 1.f};
    ga.seg[3] = {qlat, wuq, u_q_b, Qc,  NC, 0, NH * NDH, SC2};
    ga.seg[4] = {qlat, wqr, qr_b,  Qrt, NC, 3, NH * NDR, SC2};
    ga.nbstart[0] = 0;  ga.nbstart[1] = 8;  ga.nbstart[2] = 16;
    ga.nbstart[3] = 20; ga.nbstart[4] = 28; ga.nbstart[5] = 32;
    gemm_bt<256><<<dim3(32, 32), dim3(512), 0, stream>>>(ga);
  }

  // 4) attention (80KB dynamic LDS, 2 blocks/CU)
  hipFuncSetAttribute((const void*)attn_kernel,
                      hipFuncAttributeMaxDynamicSharedMemorySize, 81920);
  attn_kernel<<<dim3(512), dim3(256), 81920, stream>>>(Qc, Qrt, Ktb, Vtb, ctx);

  // 5) out projection (f32 out + bias, BN=256)
  {
    GemmArgs ga;
    ga.nseg = 1;
    ga.seg[0] = {ctx, wout, out_b, d_out, NHID, 2, NHID, 1.f};
    for (int i = 1; i < 5; ++i) ga.seg[i] = ga.seg[0];
    ga.nbstart[0] = 0;
    for (int i = 1; i < 6; ++i) ga.nbstart[i] = 8;
    gemm_bt<256><<<dim3(8, 32), dim3(512), 0, stream>>>(ga);
  }
}